// Round 1
// 804.452 us; speedup vs baseline: 1.9774x; 1.9774x over previous
//
#include <hip/hip_runtime.h>
#include <hip/hip_bf16.h>
#include <math.h>

// MoE top-2, T=8192 tokens, D=1024, F=4096, E=8. Inputs fp32, output fp32.
// R7: (a) atomic-free routing/placement (the 206us router was cross-XCD
//     same-cacheline atomic serialization on cnt[8]; place had the same on
//     pos[8]); (b) all-expert batched GEMM dispatches (blockIdx.z = expert)
//     so the GPU is fully occupied instead of 128-512 blocks per launch.
//
// ws layout: lists(~0.6 MiB) | y 32MiB | xg 32MiB | w1b 64MiB | w2b 64MiB |
//            h (batched: 128MiB @16384 rows; fallback: 32MiB @4096 rows)

#define D_DIM 1024
#define F_DIM 4096
#define E_NUM 8
#define T_NUM 8192
#define MAX_ROWS 4096
#define BM 128
#define BN 128
#define BK 32
#define PBLK 32   // placement blocks (256 tokens each)

typedef __bf16 bf16x8_t __attribute__((ext_vector_type(8)));
typedef __bf16 bf16x4_t __attribute__((ext_vector_type(4)));
typedef float f32x4_t __attribute__((ext_vector_type(4)));
using bf16 = __hip_bfloat16;

typedef __attribute__((address_space(1))) const void gvoid_t;
typedef __attribute__((address_space(3))) void svoid_t;

__device__ __forceinline__ void async16(void* lds, const void* g) {
    __builtin_amdgcn_global_load_lds((gvoid_t*)g, (svoid_t*)lds, 16, 0, 0);
}

__device__ __forceinline__ bf16x8_t cvt8(const float* __restrict__ p) {
    float4 f0 = *(const float4*)(p);
    float4 f1 = *(const float4*)(p + 4);
    bf16x8_t r;
    r[0] = (__bf16)f0.x; r[1] = (__bf16)f0.y; r[2] = (__bf16)f0.z; r[3] = (__bf16)f0.w;
    r[4] = (__bf16)f1.x; r[5] = (__bf16)f1.y; r[6] = (__bf16)f1.z; r[7] = (__bf16)f1.w;
    return r;
}

__device__ __forceinline__ float gelu(float v) {
    return 0.5f * v * (1.0f + erff(v * 0.70710678118654752f));
}

// ---------------- router: fp64-accum scores, top-2, softmax. NO atomics. -----
// 4 tokens per 256-thread block (one wave per token, same math as before).
__global__ __launch_bounds__(256) void moe_router(
    const float* __restrict__ x, const float* __restrict__ rw,
    int* __restrict__ tok_e, float* __restrict__ tok_w)
{
    const int t = blockIdx.x * 4 + (threadIdx.x >> 6);
    const int lane = threadIdx.x & 63;
    float xv[16];
#pragma unroll
    for (int j = 0; j < 16; ++j) xv[j] = x[(size_t)t * D_DIM + lane + 64 * j];
    double s[E_NUM];
#pragma unroll
    for (int e = 0; e < E_NUM; ++e) {
        const float* w = rw + e * D_DIM;
        double a = 0.0;
#pragma unroll
        for (int j = 0; j < 16; ++j) a += (double)xv[j] * (double)w[lane + 64 * j];
#pragma unroll
        for (int off = 32; off > 0; off >>= 1) a += __shfl_xor(a, off, 64);
        s[e] = a;
    }
    if (lane == 0) {
        int i0 = 0; double v0 = s[0];
#pragma unroll
        for (int e = 1; e < E_NUM; ++e) if (s[e] > v0) { v0 = s[e]; i0 = e; }
        int i1 = (i0 == 0) ? 1 : 0; double v1 = s[i1];
#pragma unroll
        for (int e = 0; e < E_NUM; ++e) if (e != i0 && e != i1 && s[e] > v1) { v1 = s[e]; i1 = e; }
        float e1 = expf((float)(v1 - v0));
        float inv = 1.f / (1.f + e1);
        tok_e[t * 2 + 0] = i0; tok_w[t * 2 + 0] = inv;
        tok_e[t * 2 + 1] = i1; tok_w[t * 2 + 1] = e1 * inv;
    }
}

// ---------------- count: per-block LDS histograms -> bh[PBLK][E] -------------
__global__ __launch_bounds__(256) void moe_count(
    const int* __restrict__ tok_e, int* __restrict__ bh)
{
    __shared__ int hist[E_NUM];
    const int tid = threadIdx.x, b = blockIdx.x;
    if (tid < E_NUM) hist[tid] = 0;
    __syncthreads();
    const int t = b * 256 + tid;
    atomicAdd(&hist[tok_e[t * 2 + 0]], 1);
    atomicAdd(&hist[tok_e[t * 2 + 1]], 1);
    __syncthreads();
    if (tid < E_NUM) bh[b * E_NUM + tid] = hist[tid];
}

// ---------------- scan: totals, offsets, per-block bases (serial, tiny) ------
__global__ void moe_scan2(const int* __restrict__ bh, int* __restrict__ cnt,
                          int* __restrict__ offsets, int* __restrict__ bbase)
{
    if (threadIdx.x == 0) {
        int tot[E_NUM];
#pragma unroll
        for (int e = 0; e < E_NUM; ++e) tot[e] = 0;
        for (int b = 0; b < PBLK; ++b)
#pragma unroll
            for (int e = 0; e < E_NUM; ++e) tot[e] += bh[b * E_NUM + e];
        int off = 0;
#pragma unroll
        for (int e = 0; e < E_NUM; ++e) { offsets[e] = off; cnt[e] = tot[e]; off += tot[e]; }
        int run[E_NUM];
#pragma unroll
        for (int e = 0; e < E_NUM; ++e) run[e] = 0;
        for (int b = 0; b < PBLK; ++b)
#pragma unroll
            for (int e = 0; e < E_NUM; ++e) {
                bbase[b * E_NUM + e] = offsets[e] + run[e];
                run[e] += bh[b * E_NUM + e];
            }
    }
}

// ---------------- place: LDS-atomic local ranks + precomputed bases ----------
__global__ __launch_bounds__(256) void moe_place2(
    const int* __restrict__ tok_e, const float* __restrict__ tok_w,
    const int* __restrict__ bbase,
    int* __restrict__ tok_list, float* __restrict__ wt_list,
    int* __restrict__ slot_pos)
{
    __shared__ int hist[E_NUM];
    const int tid = threadIdx.x, b = blockIdx.x;
    if (tid < E_NUM) hist[tid] = 0;
    __syncthreads();
    const int t = b * 256 + tid;
#pragma unroll
    for (int k = 0; k < 2; ++k) {
        const int e = tok_e[t * 2 + k];
        const int lr = atomicAdd(&hist[e], 1);
        int row = bbase[b * E_NUM + e] + lr;
        if (row >= 2 * T_NUM) row = 2 * T_NUM - 1;
        tok_list[row] = t;
        wt_list[row] = tok_w[t * 2 + k];
        slot_pos[t * 2 + k] = row;
    }
}

// ---------------- prep: fp32 -> bf16 weight convert ----------------
__global__ __launch_bounds__(256) void cvt_f32_bf16(
    const float* __restrict__ src, __bf16* __restrict__ dst, int n)
{
    const int i = (blockIdx.x * 256 + threadIdx.x) * 4;
    if (i >= n) return;
    float4 v = *(const float4*)(src + i);
    bf16x4_t o;
    o[0] = (__bf16)v.x; o[1] = (__bf16)v.y; o[2] = (__bf16)v.z; o[3] = (__bf16)v.w;
    *(bf16x4_t*)(dst + i) = o;
}

// ---------------- prep: gather-convert x rows into slot order ----------------
__global__ __launch_bounds__(256) void moe_gather(
    const float* __restrict__ x, const int* __restrict__ tok_list,
    __bf16* __restrict__ xg)
{
    const int row = blockIdx.x;
    const int c = threadIdx.x * 4;
    int tok = tok_list[row];
    if ((unsigned)tok >= T_NUM) tok = 0;
    float4 v = *(const float4*)(x + (size_t)tok * D_DIM + c);
    bf16x4_t o;
    o[0] = (__bf16)v.x; o[1] = (__bf16)v.y; o[2] = (__bf16)v.z; o[3] = (__bf16)v.w;
    *(bf16x4_t*)(xg + (size_t)row * D_DIM + c) = o;
}

// ======== batched GEMM1: h[slot] = gelu(xg_seg @ W1b[e]^T) * wt ==============
// grid (F/128, MAX_ROWS/128, E), block 256. h indexed by GLOBAL slot row.
__global__ __launch_bounds__(256) void moe_gemm1_b(
    const __bf16* __restrict__ xg, const __bf16* __restrict__ w1b,
    const float* __restrict__ wt_list,
    const int* __restrict__ offsets, const int* __restrict__ cnt,
    __bf16* __restrict__ h)
{
    const int e = blockIdx.z;
    int M = cnt[e]; if (M > MAX_ROWS) M = MAX_ROWS;
    const int m0 = blockIdx.y * BM;
    if (m0 >= M) return;
    const int off_e = offsets[e];
    const int n0 = blockIdx.x * BN;

    __shared__ __bf16 As[BM * BK];
    __shared__ __bf16 Bs[BN * BK];

    const int tid = threadIdx.x;
    const int wave = tid >> 6;
    const int lane = tid & 63;
    const int quad = lane >> 4;
    const int l16 = lane & 15;
    const int wm = (wave >> 1) * 64;
    const int wn = (wave & 1) * 64;

    const int kc = (tid & 3) * 8;
    const int r0 = m0 + (tid >> 2);
    const int r1 = r0 + 64;
    const __bf16* a0 = xg + (size_t)(off_e + (r0 < M ? r0 : M - 1)) * D_DIM + kc;
    const __bf16* a1 = xg + (size_t)(off_e + (r1 < M ? r1 : M - 1)) * D_DIM + kc;
    const __bf16* b0 = w1b + ((size_t)e * F_DIM + n0 + (tid >> 2)) * D_DIM + kc;
    const __bf16* b1 = b0 + (size_t)64 * D_DIM;
    __bf16* asb0 = As + (size_t)(wave * 64) * 8;
    __bf16* asb1 = As + (size_t)(256 + wave * 64) * 8;
    __bf16* bsb0 = Bs + (size_t)(wave * 64) * 8;
    __bf16* bsb1 = Bs + (size_t)(256 + wave * 64) * 8;

    f32x4_t acc[4][4];
#pragma unroll
    for (int i = 0; i < 4; ++i)
#pragma unroll
        for (int j = 0; j < 4; ++j) acc[i][j] = (f32x4_t){0.f, 0.f, 0.f, 0.f};

    for (int k0 = 0; k0 < D_DIM; k0 += BK) {
        __syncthreads();
        async16(asb0, a0 + k0);
        async16(asb1, a1 + k0);
        async16(bsb0, b0 + k0);
        async16(bsb1, b1 + k0);
        __syncthreads();
        bf16x8_t af[4], bfr[4];
#pragma unroll
        for (int mi = 0; mi < 4; ++mi)
            af[mi] = *(const bf16x8_t*)&As[(wm + mi * 16 + l16) * BK + quad * 8];
#pragma unroll
        for (int ni = 0; ni < 4; ++ni)
            bfr[ni] = *(const bf16x8_t*)&Bs[(wn + ni * 16 + l16) * BK + quad * 8];
#pragma unroll
        for (int mi = 0; mi < 4; ++mi)
#pragma unroll
            for (int ni = 0; ni < 4; ++ni)
                acc[mi][ni] = __builtin_amdgcn_mfma_f32_16x16x32_bf16(
                    af[mi], bfr[ni], acc[mi][ni], 0, 0, 0);
    }

#pragma unroll
    for (int mi = 0; mi < 4; ++mi) {
#pragma unroll
        for (int reg = 0; reg < 4; ++reg) {
            const int r = m0 + wm + mi * 16 + quad * 4 + reg;
            if (r < M) {
                const float wgt = wt_list[off_e + r];
#pragma unroll
                for (int ni = 0; ni < 4; ++ni) {
                    const int col = n0 + wn + ni * 16 + l16;
                    h[(size_t)(off_e + r) * F_DIM + col] = (__bf16)(gelu(acc[mi][ni][reg]) * wgt);
                }
            }
        }
    }
}

// ======== batched GEMM2: y[slot] = h[slot] @ W2b[e]^T ========================
// grid (D/128, MAX_ROWS/128, E), block 256.
__global__ __launch_bounds__(256) void moe_gemm2_b(
    const __bf16* __restrict__ h, const __bf16* __restrict__ w2b,
    const int* __restrict__ offsets, const int* __restrict__ cnt,
    __bf16* __restrict__ y)
{
    const int e = blockIdx.z;
    int M = cnt[e]; if (M > MAX_ROWS) M = MAX_ROWS;
    const int m0 = blockIdx.y * BM;
    if (m0 >= M) return;
    const int off_e = offsets[e];
    const int n0 = blockIdx.x * BN;

    __shared__ __bf16 As[BM * BK];
    __shared__ __bf16 Bs[BN * BK];

    const int tid = threadIdx.x;
    const int wave = tid >> 6;
    const int lane = tid & 63;
    const int quad = lane >> 4;
    const int l16 = lane & 15;
    const int wm = (wave >> 1) * 64;
    const int wn = (wave & 1) * 64;

    const int kc = (tid & 3) * 8;
    const int r0 = m0 + (tid >> 2);
    const int r1 = r0 + 64;
    const __bf16* a0 = h + (size_t)(off_e + (r0 < M ? r0 : M - 1)) * F_DIM + kc;
    const __bf16* a1 = h + (size_t)(off_e + (r1 < M ? r1 : M - 1)) * F_DIM + kc;
    const __bf16* b0 = w2b + ((size_t)e * D_DIM + n0 + (tid >> 2)) * F_DIM + kc;
    const __bf16* b1 = b0 + (size_t)64 * F_DIM;
    __bf16* asb0 = As + (size_t)(wave * 64) * 8;
    __bf16* asb1 = As + (size_t)(256 + wave * 64) * 8;
    __bf16* bsb0 = Bs + (size_t)(wave * 64) * 8;
    __bf16* bsb1 = Bs + (size_t)(256 + wave * 64) * 8;

    f32x4_t acc[4][4];
#pragma unroll
    for (int i = 0; i < 4; ++i)
#pragma unroll
        for (int j = 0; j < 4; ++j) acc[i][j] = (f32x4_t){0.f, 0.f, 0.f, 0.f};

    for (int k0 = 0; k0 < F_DIM; k0 += BK) {
        __syncthreads();
        async16(asb0, a0 + k0);
        async16(asb1, a1 + k0);
        async16(bsb0, b0 + k0);
        async16(bsb1, b1 + k0);
        __syncthreads();
        bf16x8_t af[4], bfr[4];
#pragma unroll
        for (int mi = 0; mi < 4; ++mi)
            af[mi] = *(const bf16x8_t*)&As[(wm + mi * 16 + l16) * BK + quad * 8];
#pragma unroll
        for (int ni = 0; ni < 4; ++ni)
            bfr[ni] = *(const bf16x8_t*)&Bs[(wn + ni * 16 + l16) * BK + quad * 8];
#pragma unroll
        for (int mi = 0; mi < 4; ++mi)
#pragma unroll
            for (int ni = 0; ni < 4; ++ni)
                acc[mi][ni] = __builtin_amdgcn_mfma_f32_16x16x32_bf16(
                    af[mi], bfr[ni], acc[mi][ni], 0, 0, 0);
    }

#pragma unroll
    for (int mi = 0; mi < 4; ++mi) {
#pragma unroll
        for (int reg = 0; reg < 4; ++reg) {
            const int r = m0 + wm + mi * 16 + quad * 4 + reg;
            if (r < M) {
#pragma unroll
                for (int ni = 0; ni < 4; ++ni) {
                    const int col = n0 + wn + ni * 16 + l16;
                    y[(size_t)(off_e + r) * D_DIM + col] = (__bf16)acc[mi][ni][reg];
                }
            }
        }
    }
}

// ======== fallback per-expert fast GEMMs (h local-row indexed, 32 MiB) =======
__global__ __launch_bounds__(256) void moe_gemm1_f(
    const __bf16* __restrict__ xg, const __bf16* __restrict__ w1b,
    const float* __restrict__ wt_list,
    const int* __restrict__ offsets, const int* __restrict__ cnt,
    __bf16* __restrict__ h, int e)
{
    int M = cnt[e]; if (M > MAX_ROWS) M = MAX_ROWS;
    const int m0 = blockIdx.y * BM;
    if (m0 >= M) return;
    const int off_e = offsets[e];
    const int n0 = blockIdx.x * BN;

    __shared__ __bf16 As[BM * BK];
    __shared__ __bf16 Bs[BN * BK];

    const int tid = threadIdx.x;
    const int wave = tid >> 6;
    const int lane = tid & 63;
    const int quad = lane >> 4;
    const int l16 = lane & 15;
    const int wm = (wave >> 1) * 64;
    const int wn = (wave & 1) * 64;

    const int kc = (tid & 3) * 8;
    const int r0 = m0 + (tid >> 2);
    const int r1 = r0 + 64;
    const __bf16* a0 = xg + (size_t)(off_e + (r0 < M ? r0 : M - 1)) * D_DIM + kc;
    const __bf16* a1 = xg + (size_t)(off_e + (r1 < M ? r1 : M - 1)) * D_DIM + kc;
    const __bf16* b0 = w1b + ((size_t)e * F_DIM + n0 + (tid >> 2)) * D_DIM + kc;
    const __bf16* b1 = b0 + (size_t)64 * D_DIM;
    __bf16* asb0 = As + (size_t)(wave * 64) * 8;
    __bf16* asb1 = As + (size_t)(256 + wave * 64) * 8;
    __bf16* bsb0 = Bs + (size_t)(wave * 64) * 8;
    __bf16* bsb1 = Bs + (size_t)(256 + wave * 64) * 8;

    f32x4_t acc[4][4];
#pragma unroll
    for (int i = 0; i < 4; ++i)
#pragma unroll
        for (int j = 0; j < 4; ++j) acc[i][j] = (f32x4_t){0.f, 0.f, 0.f, 0.f};

    for (int k0 = 0; k0 < D_DIM; k0 += BK) {
        __syncthreads();
        async16(asb0, a0 + k0);
        async16(asb1, a1 + k0);
        async16(bsb0, b0 + k0);
        async16(bsb1, b1 + k0);
        __syncthreads();
        bf16x8_t af[4], bfr[4];
#pragma unroll
        for (int mi = 0; mi < 4; ++mi)
            af[mi] = *(const bf16x8_t*)&As[(wm + mi * 16 + l16) * BK + quad * 8];
#pragma unroll
        for (int ni = 0; ni < 4; ++ni)
            bfr[ni] = *(const bf16x8_t*)&Bs[(wn + ni * 16 + l16) * BK + quad * 8];
#pragma unroll
        for (int mi = 0; mi < 4; ++mi)
#pragma unroll
            for (int ni = 0; ni < 4; ++ni)
                acc[mi][ni] = __builtin_amdgcn_mfma_f32_16x16x32_bf16(
                    af[mi], bfr[ni], acc[mi][ni], 0, 0, 0);
    }

#pragma unroll
    for (int mi = 0; mi < 4; ++mi) {
#pragma unroll
        for (int reg = 0; reg < 4; ++reg) {
            const int r = m0 + wm + mi * 16 + quad * 4 + reg;
            if (r < M) {
                const float wgt = wt_list[off_e + r];
#pragma unroll
                for (int ni = 0; ni < 4; ++ni) {
                    const int col = n0 + wn + ni * 16 + l16;
                    h[(size_t)r * F_DIM + col] = (__bf16)(gelu(acc[mi][ni][reg]) * wgt);
                }
            }
        }
    }
}

__global__ __launch_bounds__(256) void moe_gemm2_f(
    const __bf16* __restrict__ h, const __bf16* __restrict__ w2b,
    const int* __restrict__ offsets, const int* __restrict__ cnt,
    __bf16* __restrict__ y, int e)
{
    int M = cnt[e]; if (M > MAX_ROWS) M = MAX_ROWS;
    const int m0 = blockIdx.y * BM;
    if (m0 >= M) return;
    const int off_e = offsets[e];
    const int n0 = blockIdx.x * BN;

    __shared__ __bf16 As[BM * BK];
    __shared__ __bf16 Bs[BN * BK];

    const int tid = threadIdx.x;
    const int wave = tid >> 6;
    const int lane = tid & 63;
    const int quad = lane >> 4;
    const int l16 = lane & 15;
    const int wm = (wave >> 1) * 64;
    const int wn = (wave & 1) * 64;

    const int kc = (tid & 3) * 8;
    const int r0 = m0 + (tid >> 2);
    const int r1 = r0 + 64;
    const __bf16* a0 = h + (size_t)(r0 < M ? r0 : M - 1) * F_DIM + kc;
    const __bf16* a1 = h + (size_t)(r1 < M ? r1 : M - 1) * F_DIM + kc;
    const __bf16* b0 = w2b + ((size_t)e * D_DIM + n0 + (tid >> 2)) * F_DIM + kc;
    const __bf16* b1 = b0 + (size_t)64 * F_DIM;
    __bf16* asb0 = As + (size_t)(wave * 64) * 8;
    __bf16* asb1 = As + (size_t)(256 + wave * 64) * 8;
    __bf16* bsb0 = Bs + (size_t)(wave * 64) * 8;
    __bf16* bsb1 = Bs + (size_t)(256 + wave * 64) * 8;

    f32x4_t acc[4][4];
#pragma unroll
    for (int i = 0; i < 4; ++i)
#pragma unroll
        for (int j = 0; j < 4; ++j) acc[i][j] = (f32x4_t){0.f, 0.f, 0.f, 0.f};

    for (int k0 = 0; k0 < F_DIM; k0 += BK) {
        __syncthreads();
        async16(asb0, a0 + k0);
        async16(asb1, a1 + k0);
        async16(bsb0, b0 + k0);
        async16(bsb1, b1 + k0);
        __syncthreads();
        bf16x8_t af[4], bfr[4];
#pragma unroll
        for (int mi = 0; mi < 4; ++mi)
            af[mi] = *(const bf16x8_t*)&As[(wm + mi * 16 + l16) * BK + quad * 8];
#pragma unroll
        for (int ni = 0; ni < 4; ++ni)
            bfr[ni] = *(const bf16x8_t*)&Bs[(wn + ni * 16 + l16) * BK + quad * 8];
#pragma unroll
        for (int mi = 0; mi < 4; ++mi)
#pragma unroll
            for (int ni = 0; ni < 4; ++ni)
                acc[mi][ni] = __builtin_amdgcn_mfma_f32_16x16x32_bf16(
                    af[mi], bfr[ni], acc[mi][ni], 0, 0, 0);
    }

#pragma unroll
    for (int mi = 0; mi < 4; ++mi) {
#pragma unroll
        for (int reg = 0; reg < 4; ++reg) {
            const int r = m0 + wm + mi * 16 + quad * 4 + reg;
            if (r < M) {
#pragma unroll
                for (int ni = 0; ni < 4; ++ni) {
                    const int col = n0 + wn + ni * 16 + l16;
                    y[(size_t)(off_e + r) * D_DIM + col] = (__bf16)acc[mi][ni][reg];
                }
            }
        }
    }
}

// ---------------- combine: out[t] = y[slot0] + y[slot1], fp32 out ------------
__global__ __launch_bounds__(256) void moe_combine(
    const __bf16* __restrict__ y, const int* __restrict__ slot_pos,
    float* __restrict__ out)
{
    const size_t i = ((size_t)blockIdx.x * blockDim.x + threadIdx.x) * 4;
    const int t = (int)(i >> 10);
    const int d = (int)(i & (D_DIM - 1));
    int r0 = slot_pos[t * 2 + 0];
    int r1 = slot_pos[t * 2 + 1];
    if ((unsigned)r0 >= 2 * T_NUM) r0 = 0;
    if ((unsigned)r1 >= 2 * T_NUM) r1 = 0;
    bf16x4_t a = *(const bf16x4_t*)(y + (size_t)r0 * D_DIM + d);
    bf16x4_t b = *(const bf16x4_t*)(y + (size_t)r1 * D_DIM + d);
    float4 oo;
    oo.x = (float)a[0] + (float)b[0];
    oo.y = (float)a[1] + (float)b[1];
    oo.z = (float)a[2] + (float)b[2];
    oo.w = (float)a[3] + (float)b[3];
    *(float4*)(out + i) = oo;
}

// ================= slow fallback (R5): 16x16 per-wave tiles ==================
__global__ __launch_bounds__(256) void moe_gemm1_s(
    const float* __restrict__ x, const float* __restrict__ w1,
    const int* __restrict__ tok_list, const float* __restrict__ wt_list,
    const int* __restrict__ offsets, const int* __restrict__ cnt,
    bf16* __restrict__ h, int e)
{
    int M = cnt[e]; if (M > MAX_ROWS) M = MAX_ROWS;
    const int m0 = blockIdx.y * 16;
    if (m0 >= M) return;
    const int off_e = offsets[e];
    const int wave = threadIdx.x >> 6;
    const int lane = threadIdx.x & 63;
    const int quad = lane >> 4;
    const int l16 = lane & 15;
    const int n0 = blockIdx.x * 64 + wave * 16;

    const int arow = m0 + l16;
    int tok = tok_list[off_e + (arow < M ? arow : M - 1)];
    if ((unsigned)tok >= T_NUM) tok = 0;
    const float* aptr = x + (size_t)tok * D_DIM + quad * 8;
    const float* bptr = w1 + ((size_t)e * F_DIM + n0 + l16) * D_DIM + quad * 8;

    f32x4_t acc = {0.f, 0.f, 0.f, 0.f};
#pragma unroll 4
    for (int k0 = 0; k0 < D_DIM; k0 += 32) {
        acc = __builtin_amdgcn_mfma_f32_16x16x32_bf16(cvt8(aptr + k0), cvt8(bptr + k0), acc, 0, 0, 0);
    }
    const int col = n0 + l16;
#pragma unroll
    for (int reg = 0; reg < 4; ++reg) {
        const int r = m0 + quad * 4 + reg;
        if (r < M) {
            float wgt = wt_list[off_e + r];
            h[(size_t)r * F_DIM + col] = __float2bfloat16(gelu(acc[reg]) * wgt);
        }
    }
}

__global__ __launch_bounds__(256) void moe_gemm2_s(
    const bf16* __restrict__ h, const float* __restrict__ w2,
    const int* __restrict__ offsets, const int* __restrict__ cnt,
    bf16* __restrict__ y, int e)
{
    int M = cnt[e]; if (M > MAX_ROWS) M = MAX_ROWS;
    const int m0 = blockIdx.y * 16;
    if (m0 >= M) return;
    const int off_e = offsets[e];
    const int wave = threadIdx.x >> 6;
    const int lane = threadIdx.x & 63;
    const int quad = lane >> 4;
    const int l16 = lane & 15;
    const int n0 = blockIdx.x * 64 + wave * 16;

    const int arow = m0 + l16;
    const int hrow = (arow < M ? arow : M - 1);
    const bf16* aptr = h + (size_t)hrow * F_DIM + quad * 8;
    const float* bptr = w2 + ((size_t)e * D_DIM + n0 + l16) * F_DIM + quad * 8;

    f32x4_t acc = {0.f, 0.f, 0.f, 0.f};
#pragma unroll 4
    for (int k0 = 0; k0 < F_DIM; k0 += 32) {
        acc = __builtin_amdgcn_mfma_f32_16x16x32_bf16(*(const bf16x8_t*)(aptr + k0), cvt8(bptr + k0), acc, 0, 0, 0);
    }
    const int col = n0 + l16;
#pragma unroll
    for (int reg = 0; reg < 4; ++reg) {
        const int r = m0 + quad * 4 + reg;
        if (r < M) {
            int yrow = off_e + r;
            if ((unsigned)yrow >= 2 * T_NUM) yrow = 0;
            y[(size_t)yrow * D_DIM + col] = __float2bfloat16(acc[reg]);
        }
    }
}

extern "C" void kernel_launch(void* const* d_in, const int* in_sizes, int n_in,
                              void* d_out, int out_size, void* d_ws, size_t ws_size,
                              hipStream_t stream) {
    const float* x  = (const float*)d_in[0];
    const float* rw = (const float*)d_in[1];
    const float* w1 = (const float*)d_in[2];
    const float* w2 = (const float*)d_in[3];
    float* out = (float*)d_out;

    char* ws = (char*)d_ws;
    size_t o = 0;
    int*   tok_e    = (int*)(ws + o);   o += (size_t)T_NUM * 2 * 4;
    float* tok_w    = (float*)(ws + o); o += (size_t)T_NUM * 2 * 4;
    int*   tok_list = (int*)(ws + o);   o += (size_t)2 * T_NUM * 4;
    float* wt_list  = (float*)(ws + o); o += (size_t)2 * T_NUM * 4;
    int*   slot_pos = (int*)(ws + o);   o += (size_t)2 * T_NUM * 4;
    int*   cnt      = (int*)(ws + o);   o += 32;
    int*   offsets  = (int*)(ws + o);   o += 32;
    int*   bh       = (int*)(ws + o);   o += (size_t)PBLK * E_NUM * 4;
    int*   bbase    = (int*)(ws + o);   o += (size_t)PBLK * E_NUM * 4;
    o = (o + 255) & ~(size_t)255;
    bf16*  y        = (bf16*)(ws + o);  o += (size_t)2 * T_NUM * D_DIM * 2;     // 32 MiB
    const size_t o_after_y = o;
    __bf16* xg  = (__bf16*)(ws + o);    o += (size_t)2 * T_NUM * D_DIM * 2;     // 32 MiB
    __bf16* w1b = (__bf16*)(ws + o);    o += (size_t)E_NUM * F_DIM * D_DIM * 2; // 64 MiB
    __bf16* w2b = (__bf16*)(ws + o);    o += (size_t)E_NUM * D_DIM * F_DIM * 2; // 64 MiB
    __bf16* h   = (__bf16*)(ws + o);    // batched: 128 MiB / fallback: 32 MiB
    const size_t need_fast  = o + (size_t)MAX_ROWS * F_DIM * 2;
    const size_t need_batch = o + (size_t)2 * T_NUM * F_DIM * 2;
    bf16* h_slow = (bf16*)(ws + o_after_y);   // slow path overlaps xg region

    // ---- routing (zero global atomics) ----
    moe_router<<<T_NUM / 4, 256, 0, stream>>>(x, rw, tok_e, tok_w);
    moe_count<<<PBLK, 256, 0, stream>>>(tok_e, bh);
    moe_scan2<<<1, 64, 0, stream>>>(bh, cnt, offsets, bbase);
    moe_place2<<<PBLK, 256, 0, stream>>>(tok_e, tok_w, bbase,
                                         tok_list, wt_list, slot_pos);

    if (ws_size >= need_batch) {
        const int nw = E_NUM * F_DIM * D_DIM;  // 33.5M elems each
        cvt_f32_bf16<<<nw / 1024, 256, 0, stream>>>(w1, w1b, nw);
        cvt_f32_bf16<<<nw / 1024, 256, 0, stream>>>(w2, w2b, nw);
        moe_gather<<<2 * T_NUM, 256, 0, stream>>>(x, tok_list, xg);
        moe_gemm1_b<<<dim3(F_DIM / BN, MAX_ROWS / BM, E_NUM), 256, 0, stream>>>(
            xg, w1b, wt_list, offsets, cnt, h);
        moe_gemm2_b<<<dim3(D_DIM / BN, MAX_ROWS / BM, E_NUM), 256, 0, stream>>>(
            h, w2b, offsets, cnt, (__bf16*)y);
    } else if (ws_size >= need_fast) {
        const int nw = E_NUM * F_DIM * D_DIM;
        cvt_f32_bf16<<<nw / 1024, 256, 0, stream>>>(w1, w1b, nw);
        cvt_f32_bf16<<<nw / 1024, 256, 0, stream>>>(w2, w2b, nw);
        moe_gather<<<2 * T_NUM, 256, 0, stream>>>(x, tok_list, xg);
        for (int e = 0; e < E_NUM; ++e) {
            moe_gemm1_f<<<dim3(F_DIM / BN, MAX_ROWS / BM), 256, 0, stream>>>(
                xg, w1b, wt_list, offsets, cnt, h, e);
            moe_gemm2_f<<<dim3(D_DIM / BN, MAX_ROWS / BM), 256, 0, stream>>>(
                h, w2b, offsets, cnt, (__bf16*)y, e);
        }
    } else {
        for (int e = 0; e < E_NUM; ++e) {
            moe_gemm1_s<<<dim3(F_DIM / 64, MAX_ROWS / 16), 256, 0, stream>>>(
                x, w1, tok_list, wt_list, offsets, cnt, h_slow, e);
            moe_gemm2_s<<<dim3(D_DIM / 64, MAX_ROWS / 16), 256, 0, stream>>>(
                h_slow, w2, offsets, cnt, y, e);
        }
    }
    moe_combine<<<T_NUM * D_DIM / 1024, 256, 0, stream>>>((const __bf16*)y, slot_pos, out);
}